// Round 3
// baseline (208.102 us; speedup 1.0000x reference)
//
#include <hip/hip_runtime.h>

#define KTOP 100
#define NCOL 16384
#define TPB  256
#define NCHUNK (NCOL / (TPB * 4))   // 16 uint4 per thread
#define HW0  1032                   // pass-0: 1024 words (2048 packed bins) + 8 pad (copies 8 banks apart)
#define HW1  136                    // passes 1-3: 128 words + 8 pad
#define CAP  2048                   // LDS candidate list capacity

// order-preserving key transform: a<b (float, incl. sign) <=> enc(a)<enc(b) (uint)
__device__ __forceinline__ unsigned enc(unsigned u) {
    return u ^ (((unsigned)((int)u >> 31)) | 0x80000000u);
}

__global__ __launch_bounds__(TPB, 6)
void topk_act_kernel(const float* __restrict__ x, float* __restrict__ out) {
    __shared__ unsigned hist[4 * HW0];     // 16.5 KB, reused by all passes
    __shared__ unsigned cand[CAP];         // 8 KB candidate keys
    __shared__ unsigned scan_arr[TPB];
    __shared__ unsigned s_cnt;

    const int row  = blockIdx.x;
    const int tid  = threadIdx.x;
    const int lane = tid & 63;
    const int wv   = tid >> 6;

    const uint4* __restrict__ xrow = (const uint4*)(x + (size_t)row * NCOL);
    uint4* __restrict__ orow = (uint4*)(out + (size_t)row * NCOL);

    // ---- zero pass-0 histogram ----
    for (int i = tid; i < 4 * HW0; i += TPB) hist[i] = 0;
    if (tid == 0) s_cnt = 0;
    __syncthreads();

    // ---- pass 0: 11-bit bins, packed 2x16-bit counters, per-wave copies ----
    unsigned* myh = hist + wv * HW0;
    #pragma unroll
    for (int j = 0; j < NCHUNK; ++j) {
        uint4 v = xrow[tid + j * TPB];
        unsigned k0 = enc(v.x), k1 = enc(v.y), k2 = enc(v.z), k3 = enc(v.w);
        atomicAdd(&myh[k0 >> 22], 1u << (((k0 >> 21) & 1u) << 4));
        atomicAdd(&myh[k1 >> 22], 1u << (((k1 >> 21) & 1u) << 4));
        atomicAdd(&myh[k2 >> 22], 1u << (((k2 >> 21) & 1u) << 4));
        atomicAdd(&myh[k3 >> 22], 1u << (((k3 >> 21) & 1u) << 4));
    }
    __syncthreads();

    // ---- pass-0 boundary scan (wave-redundant, no barriers) ----
    unsigned kcur = KTOP, eqc = 0, pref = 0;
    {
        unsigned own = 0;
        const int bw = 16 * lane;
        #pragma unroll
        for (int w = 0; w < 16; ++w) {
            unsigned s = hist[0 * HW0 + bw + w] + hist[1 * HW0 + bw + w]
                       + hist[2 * HW0 + bw + w] + hist[3 * HW0 + bw + w];
            own += (s & 0xFFFFu) + (s >> 16);
        }
        unsigned incl = own;
        #pragma unroll
        for (int s = 1; s < 64; s <<= 1) {
            unsigned v = __shfl_down(incl, s);
            if (lane + s < 64) incl += v;
        }
        unsigned above = incl - own;                 // count in lanes > lane
        bool hit = (above < kcur) && (above + own >= kcur);
        unsigned long long bal = __ballot(hit);
        int L = __ffsll((long long)bal) - 1;         // exactly one lane hits
        unsigned run = __shfl(above, L);
        unsigned sel_bin = 0, sel_k = 1, sel_eq = 1;
        #pragma unroll
        for (int w = 15; w >= 0; --w) {              // walk lane L's 32 bins, high->low
            unsigned s = hist[0 * HW0 + 16 * L + w] + hist[1 * HW0 + 16 * L + w]
                       + hist[2 * HW0 + 16 * L + w] + hist[3 * HW0 + 16 * L + w];
            unsigned chi = s >> 16, clo = s & 0xFFFFu;
            unsigned r1 = run + chi;                 // bin 2w+1 (higher)
            if ((run < kcur) && (r1 >= kcur)) { sel_bin = 32u * L + 2u * w + 1u; sel_k = kcur - run; sel_eq = chi; }
            unsigned r2 = r1 + clo;                  // bin 2w
            if ((r1 < kcur) && (r2 >= kcur)) { sel_bin = 32u * L + 2u * w;      sel_k = kcur - r1;  sel_eq = clo; }
            run = r2;
        }
        pref = sel_bin << 21;
        kcur = sel_k;
        eqc  = sel_eq;
    }

    // ---- extract candidates (keys with matching top-11 bits) into LDS list ----
    const unsigned bin0 = pref >> 21;
    #pragma unroll
    for (int j = 0; j < NCHUNK; ++j) {
        uint4 v = xrow[tid + j * TPB];
        unsigned k0 = enc(v.x), k1 = enc(v.y), k2 = enc(v.z), k3 = enc(v.w);
        if ((k0 >> 21) == bin0) { unsigned i = atomicAdd(&s_cnt, 1u); if (i < CAP) cand[i] = k0; }
        if ((k1 >> 21) == bin0) { unsigned i = atomicAdd(&s_cnt, 1u); if (i < CAP) cand[i] = k1; }
        if ((k2 >> 21) == bin0) { unsigned i = atomicAdd(&s_cnt, 1u); if (i < CAP) cand[i] = k2; }
        if ((k3 >> 21) == bin0) { unsigned i = atomicAdd(&s_cnt, 1u); if (i < CAP) cand[i] = k3; }
    }
    __syncthreads();
    const unsigned mtot = s_cnt;
    const bool use_list = (mtot <= CAP);

    // ---- passes 1-3: 7 bits each over candidate list (or global fallback) ----
    #pragma unroll
    for (int p = 1; p <= 3; ++p) {
        const int shift = 21 - 7 * p;                // 14, 7, 0
        __syncthreads();                             // protect hist from prior readers
        for (int i = tid; i < 4 * HW1; i += TPB) hist[i] = 0;
        __syncthreads();
        unsigned* mh = hist + wv * HW1;
        if (use_list) {
            for (unsigned i = tid; i < mtot; i += TPB) {
                unsigned k = cand[i];
                if (((k ^ pref) >> (shift + 7)) == 0)
                    atomicAdd(&mh[(k >> shift) & 0x7Fu], 1u);
            }
        } else {
            #pragma unroll
            for (int j = 0; j < NCHUNK; ++j) {
                uint4 v = xrow[tid + j * TPB];
                unsigned kk0 = enc(v.x), kk1 = enc(v.y), kk2 = enc(v.z), kk3 = enc(v.w);
                if (((kk0 ^ pref) >> (shift + 7)) == 0) atomicAdd(&mh[(kk0 >> shift) & 0x7Fu], 1u);
                if (((kk1 ^ pref) >> (shift + 7)) == 0) atomicAdd(&mh[(kk1 >> shift) & 0x7Fu], 1u);
                if (((kk2 ^ pref) >> (shift + 7)) == 0) atomicAdd(&mh[(kk2 >> shift) & 0x7Fu], 1u);
                if (((kk3 ^ pref) >> (shift + 7)) == 0) atomicAdd(&mh[(kk3 >> shift) & 0x7Fu], 1u);
            }
        }
        __syncthreads();
        // wave-redundant 128-bin boundary scan; lane owns bins 2*lane, 2*lane+1
        unsigned t0 = 0, t1 = 0;
        #pragma unroll
        for (int c = 0; c < 4; ++c) {
            t0 += hist[c * HW1 + 2 * lane];
            t1 += hist[c * HW1 + 2 * lane + 1];
        }
        unsigned own = t0 + t1, incl = own;
        #pragma unroll
        for (int s = 1; s < 64; s <<= 1) {
            unsigned v = __shfl_down(incl, s);
            if (lane + s < 64) incl += v;
        }
        unsigned above = incl - own;
        unsigned C1 = above + t1;
        unsigned C0 = C1 + t0;
        bool h1 = (above < kcur) && (C1 >= kcur);
        bool h0 = (C1 < kcur) && (C0 >= kcur);
        unsigned mybin = h1 ? (2u * lane + 1u) : (2u * lane);
        unsigned myk   = h1 ? (kcur - above) : (kcur - C1);
        unsigned myeq  = h1 ? t1 : t0;
        unsigned long long bal = __ballot(h0 || h1);
        int L = __ffsll((long long)bal) - 1;
        pref |= __shfl(mybin, L) << shift;
        kcur  = __shfl(myk, L);
        eqc   = __shfl(myeq, L);
    }

    const unsigned T = pref;        // key of K-th largest
    const unsigned krem = kcur;     // # of ==T to keep (stable by index)

    if (krem == eqc) {
        // ---- fast path: keep everything >= T (re-read x, L2-warm) ----
        #pragma unroll
        for (int j = 0; j < NCHUNK; ++j) {
            uint4 v = xrow[tid + j * TPB];
            uint4 o;
            o.x = (enc(v.x) >= T) ? v.x : 0u;
            o.y = (enc(v.y) >= T) ? v.y : 0u;
            o.z = (enc(v.z) >= T) ? v.z : 0u;
            o.w = (enc(v.w) >= T) ? v.w : 0u;
            orow[tid + j * TPB] = o;
        }
    } else {
        // ---- rare stable tie path: keep first krem equals in column order ----
        unsigned run = 0;
        for (int j = 0; j < NCHUNK; ++j) {
            uint4 v = xrow[tid + j * TPB];
            unsigned k0 = enc(v.x), k1 = enc(v.y), k2 = enc(v.z), k3 = enc(v.w);
            unsigned e0 = (k0 == T), e1 = (k1 == T), e2 = (k2 == T), e3 = (k3 == T);
            unsigned le = e0 + e1 + e2 + e3;
            __syncthreads();
            scan_arr[tid] = le;
            __syncthreads();
            for (int s = 1; s < TPB; s <<= 1) {
                unsigned t = (tid >= s) ? scan_arr[tid - s] : 0u;
                __syncthreads();
                scan_arr[tid] += t;
                __syncthreads();
            }
            unsigned excl = scan_arr[tid] - le;
            unsigned total = scan_arr[TPB - 1];
            unsigned r0 = run + excl;
            unsigned r1 = r0 + e0, r2 = r1 + e1, r3 = r2 + e2;
            uint4 o;
            o.x = (k0 > T || (e0 && r0 < krem)) ? v.x : 0u;
            o.y = (k1 > T || (e1 && r1 < krem)) ? v.y : 0u;
            o.z = (k2 > T || (e2 && r2 < krem)) ? v.z : 0u;
            o.w = (k3 > T || (e3 && r3 < krem)) ? v.w : 0u;
            orow[tid + j * TPB] = o;
            run += total;
        }
    }
}

extern "C" void kernel_launch(void* const* d_in, const int* in_sizes, int n_in,
                              void* d_out, int out_size, void* d_ws, size_t ws_size,
                              hipStream_t stream) {
    const float* x = (const float*)d_in[0];
    float* out = (float*)d_out;
    const int B = in_sizes[0] / NCOL;   // 4096 rows
    topk_act_kernel<<<B, TPB, 0, stream>>>(x, out);
}

// Round 4
// 153.436 us; speedup vs baseline: 1.3563x; 1.3563x over previous
//
#include <hip/hip_runtime.h>

#define KTOP 100
#define NCOL 16384
#define TPB  512
#define NCHUNK (NCOL / (TPB * 4))   // 8 uint4 per thread
#define HW0  1032                   // pass-0 copy stride: 1024 words (2048 packed bins) + 8 pad
#define HW1  128                    // passes 1-3: 128 bins, single copy
#define CAP  1024                   // candidate list capacity

// order-preserving key transform: a<b (float) <=> enc(a)<enc(b) (uint); involution pair dec()
__device__ __forceinline__ unsigned enc(unsigned u) {
    return u ^ (((unsigned)((int)u >> 31)) | 0x80000000u);
}
__device__ __forceinline__ unsigned dec(unsigned k) {
    return k ^ ((k & 0x80000000u) ? 0x80000000u : 0xFFFFFFFFu);
}

__global__ __launch_bounds__(TPB, 4)
void topk_act_kernel(const float* __restrict__ x, float* __restrict__ out) {
    extern __shared__ unsigned keys[];       // 64 KB: encoded row, written once at load
    __shared__ unsigned hist[2 * HW0];       // 8.25 KB, reused by all passes
    __shared__ unsigned cand[CAP];           // 4 KB
    __shared__ unsigned scan_arr[TPB];       // 2 KB (rare tie path)
    __shared__ unsigned s_cnt;

    const int row  = blockIdx.x;
    const int tid  = threadIdx.x;
    const int lane = tid & 63;
    const int wv   = tid >> 6;

    const uint4* __restrict__ xrow = (const uint4*)(x + (size_t)row * NCOL);
    uint4* __restrict__ orow = (uint4*)(out + (size_t)row * NCOL);

    for (int i = tid; i < 2 * HW0; i += TPB) hist[i] = 0;
    if (tid == 0) s_cnt = 0;
    __syncthreads();

    // ---- single HBM read: encode -> LDS keys, histogram from registers ----
    unsigned* myh = hist + (wv & 1) * HW0;
    #pragma unroll
    for (int j = 0; j < NCHUNK; ++j) {
        uint4 v = xrow[tid + j * TPB];
        uint4 k;
        k.x = enc(v.x); k.y = enc(v.y); k.z = enc(v.z); k.w = enc(v.w);
        ((uint4*)keys)[tid + j * TPB] = k;
        atomicAdd(&myh[k.x >> 22], 1u << (((k.x >> 21) & 1u) << 4));
        atomicAdd(&myh[k.y >> 22], 1u << (((k.y >> 21) & 1u) << 4));
        atomicAdd(&myh[k.z >> 22], 1u << (((k.z >> 21) & 1u) << 4));
        atomicAdd(&myh[k.w >> 22], 1u << (((k.w >> 21) & 1u) << 4));
    }
    __syncthreads();

    // ---- pass-0 boundary scan over 2048 bins (wave-redundant, uniform result) ----
    unsigned pref, kcur, eqc;
    {
        unsigned own = 0;
        #pragma unroll
        for (int w = 0; w < 16; ++w) {
            unsigned s = hist[16 * lane + w] + hist[HW0 + 16 * lane + w];
            own += (s & 0xFFFFu) + (s >> 16);    // halves sum <= 32768: no carry
        }
        unsigned incl = own;
        #pragma unroll
        for (int s = 1; s < 64; s <<= 1) {
            unsigned v = __shfl_down(incl, s);
            if (lane + s < 64) incl += v;
        }
        unsigned above = incl - own;
        bool hit = (above < KTOP) && (above + own >= KTOP);
        unsigned long long bal = __ballot(hit);
        int L = __ffsll((long long)bal) - 1;     // exactly one lane hits
        unsigned run = __shfl(above, L);
        unsigned sel_bin = 0, sel_k = 1, sel_eq = 1;
        #pragma unroll
        for (int w = 15; w >= 0; --w) {          // walk lane L's 32 bins, high->low
            unsigned s = hist[16 * L + w] + hist[HW0 + 16 * L + w];
            unsigned chi = s >> 16, clo = s & 0xFFFFu;
            unsigned r1 = run + chi;             // bin 32L+2w+1 (higher)
            if (run < KTOP && r1 >= KTOP) { sel_bin = 32u * L + 2u * w + 1u; sel_k = KTOP - run; sel_eq = chi; }
            unsigned r2 = r1 + clo;              // bin 32L+2w
            if (r1 < KTOP && r2 >= KTOP) { sel_bin = 32u * L + 2u * w;       sel_k = KTOP - r1;  sel_eq = clo; }
            run = r2;
        }
        pref = sel_bin << 21;
        kcur = sel_k;
        eqc  = sel_eq;
    }

    bool done = (kcur == eqc);   // keep whole boundary bin: T = bin floor (low bits 0)

    if (!done) {
        // ---- extract boundary-bin candidates from LDS keys ----
        const unsigned bin0 = pref >> 21;
        #pragma unroll
        for (int j = 0; j < NCHUNK; ++j) {
            uint4 k = ((const uint4*)keys)[tid + j * TPB];
            if ((k.x >> 21) == bin0) { unsigned i = atomicAdd(&s_cnt, 1u); if (i < CAP) cand[i] = k.x; }
            if ((k.y >> 21) == bin0) { unsigned i = atomicAdd(&s_cnt, 1u); if (i < CAP) cand[i] = k.y; }
            if ((k.z >> 21) == bin0) { unsigned i = atomicAdd(&s_cnt, 1u); if (i < CAP) cand[i] = k.z; }
            if ((k.w >> 21) == bin0) { unsigned i = atomicAdd(&s_cnt, 1u); if (i < CAP) cand[i] = k.w; }
        }
        __syncthreads();
        const unsigned mtot = s_cnt;             // == eqc
        const bool use_list = (mtot <= CAP);

        // ---- passes 1-3: 7 bits each over candidate list (LDS fallback if overflow) ----
        for (int p = 1; p <= 3 && !done; ++p) {
            const int shift = 21 - 7 * p;        // 14, 7, 0
            __syncthreads();                     // protect hist from prior readers
            for (int i = tid; i < HW1; i += TPB) hist[i] = 0;
            __syncthreads();
            if (use_list) {
                for (unsigned i = tid; i < mtot; i += TPB) {
                    unsigned k = cand[i];
                    if (((k ^ pref) >> (shift + 7)) == 0)
                        atomicAdd(&hist[(k >> shift) & 0x7Fu], 1u);
                }
            } else {
                for (int i = tid; i < NCOL; i += TPB) {
                    unsigned k = keys[i];
                    if (((k ^ pref) >> (shift + 7)) == 0)
                        atomicAdd(&hist[(k >> shift) & 0x7Fu], 1u);
                }
            }
            __syncthreads();
            // wave-redundant 128-bin boundary scan; lane owns bins 2*lane, 2*lane+1
            unsigned t0 = hist[2 * lane], t1 = hist[2 * lane + 1];
            unsigned own = t0 + t1, incl = own;
            #pragma unroll
            for (int s = 1; s < 64; s <<= 1) {
                unsigned v = __shfl_down(incl, s);
                if (lane + s < 64) incl += v;
            }
            unsigned above = incl - own;
            unsigned C1 = above + t1;
            unsigned C0 = C1 + t0;
            bool h1 = (above < kcur) && (C1 >= kcur);
            bool h0 = (C1 < kcur) && (C0 >= kcur);
            unsigned mybin = h1 ? (2u * lane + 1u) : (2u * lane);
            unsigned myk   = h1 ? (kcur - above) : (kcur - C1);
            unsigned myeq  = h1 ? t1 : t0;
            unsigned long long bal = __ballot(h0 || h1);
            int L = __ffsll((long long)bal) - 1;
            pref |= __shfl(mybin, L) << shift;
            kcur  = __shfl(myk, L);
            eqc   = __shfl(myeq, L);
            if (kcur == eqc) done = true;        // T = pref (remaining low bits 0)
        }
    }

    const unsigned T = pref;
    const unsigned krem = kcur;

    if (done || krem == eqc) {
        // ---- fast path: keep everything >= T, from LDS (only HBM write) ----
        #pragma unroll
        for (int j = 0; j < NCHUNK; ++j) {
            uint4 k = ((const uint4*)keys)[tid + j * TPB];
            uint4 o;
            o.x = (k.x >= T) ? dec(k.x) : 0u;
            o.y = (k.y >= T) ? dec(k.y) : 0u;
            o.z = (k.z >= T) ? dec(k.z) : 0u;
            o.w = (k.w >= T) ? dec(k.w) : 0u;
            orow[tid + j * TPB] = o;
        }
    } else {
        // ---- rare stable tie path: keep first krem equals in column order ----
        unsigned run = 0;
        for (int j = 0; j < NCHUNK; ++j) {
            uint4 k = ((const uint4*)keys)[tid + j * TPB];
            unsigned e0 = (k.x == T), e1 = (k.y == T), e2 = (k.z == T), e3 = (k.w == T);
            unsigned le = e0 + e1 + e2 + e3;
            __syncthreads();                     // protect scan_arr reuse
            scan_arr[tid] = le;
            __syncthreads();
            for (int s = 1; s < TPB; s <<= 1) {
                unsigned t = (tid >= s) ? scan_arr[tid - s] : 0u;
                __syncthreads();
                scan_arr[tid] += t;
                __syncthreads();
            }
            unsigned excl = scan_arr[tid] - le;
            unsigned total = scan_arr[TPB - 1];
            unsigned r0 = run + excl;
            unsigned r1 = r0 + e0, r2 = r1 + e1, r3 = r2 + e2;
            uint4 o;
            o.x = (k.x > T || (e0 && r0 < krem)) ? dec(k.x) : 0u;
            o.y = (k.y > T || (e1 && r1 < krem)) ? dec(k.y) : 0u;
            o.z = (k.z > T || (e2 && r2 < krem)) ? dec(k.z) : 0u;
            o.w = (k.w > T || (e3 && r3 < krem)) ? dec(k.w) : 0u;
            orow[tid + j * TPB] = o;
            run += total;
        }
    }
}

extern "C" void kernel_launch(void* const* d_in, const int* in_sizes, int n_in,
                              void* d_out, int out_size, void* d_ws, size_t ws_size,
                              hipStream_t stream) {
    const float* x = (const float*)d_in[0];
    float* out = (float*)d_out;
    const int B = in_sizes[0] / NCOL;   // 4096 rows
    topk_act_kernel<<<B, TPB, NCOL * sizeof(unsigned), stream>>>(x, out);
}

// Round 5
// 132.468 us; speedup vs baseline: 1.5710x; 1.1583x over previous
//
#include <hip/hip_runtime.h>

#define KTOP 100
#define NCOL 16384
#define TPB  1024
#define NCHUNK (NCOL / (TPB * 4))   // 4 uint4 per thread
#define HW0  1032                   // per-copy stride: 1024 words (2048 packed bins) + 8 pad
#define CAP  1024                   // candidate list capacity

// order-preserving key transform: a<b (float) <=> enc(a)<enc(b) (uint)
__device__ __forceinline__ unsigned enc(unsigned u) {
    return u ^ (((unsigned)((int)u >> 31)) | 0x80000000u);
}
__device__ __forceinline__ unsigned dec(unsigned k) {
    return k ^ ((k & 0x80000000u) ? 0x80000000u : 0xFFFFFFFFu);
}

// boundary scan over packed-16 hist words [W0, W0+64*WPL), 2 copies at stride HW0.
// returns (bin, k-in-bin, bin-count); uniform across the wave.
__device__ __forceinline__ void boundary_scan(const unsigned* hist, int lane, unsigned kcur,
                                              int W0, int WPL,
                                              unsigned& obin, unsigned& ok, unsigned& oeq) {
    unsigned own = 0;
    for (int w = 0; w < WPL; ++w) {
        unsigned s = hist[W0 + WPL * lane + w] + hist[HW0 + W0 + WPL * lane + w];
        own += (s & 0xFFFFu) + (s >> 16);
    }
    unsigned incl = own;
    #pragma unroll
    for (int s = 1; s < 64; s <<= 1) {
        unsigned v = __shfl_down(incl, s);
        if (lane + s < 64) incl += v;
    }
    unsigned above = incl - own;
    bool hit = (above < kcur) && (above + own >= kcur);
    unsigned long long bal = __ballot(hit);
    int L = __ffsll((long long)bal) - 1;       // exactly one lane hits
    unsigned run = __shfl(above, L);           // uniform from here on (broadcast reads)
    unsigned sbin = 0, sk = 1, seq = 1;
    for (int w = WPL - 1; w >= 0; --w) {
        int W = W0 + WPL * L + w;
        unsigned s = hist[W] + hist[HW0 + W];
        unsigned chi = s >> 16, clo = s & 0xFFFFu;
        unsigned r1 = run + chi;               // bin 2W+1 (higher key range)
        if (run < kcur && r1 >= kcur) { sbin = 2u * W + 1u; sk = kcur - run; seq = chi; }
        unsigned r2 = r1 + clo;                // bin 2W
        if (r1 < kcur && r2 >= kcur) { sbin = 2u * W;       sk = kcur - r1;  seq = clo; }
        run = r2;
    }
    obin = sbin; ok = sk; oeq = seq;
}

__global__ __launch_bounds__(TPB, 8)
void topk_act_kernel(const float* __restrict__ x, float* __restrict__ out) {
    extern __shared__ unsigned keys[];       // 64 KB encoded row
    __shared__ unsigned hist[2 * HW0];       // 8.25 KB (also reused as tie-path scan buffer)
    __shared__ unsigned cand[CAP];           // 4 KB
    __shared__ unsigned s_cnt, s_pos;

    const int row  = blockIdx.x;
    const int tid  = threadIdx.x;
    const int lane = tid & 63;
    const int wv   = tid >> 6;

    const uint4* __restrict__ xrow = (const uint4*)(x + (size_t)row * NCOL);
    uint4* __restrict__ orow = (uint4*)(out + (size_t)row * NCOL);

    for (int i = tid; i < 2 * HW0; i += TPB) hist[i] = 0;
    if (tid == 0) { s_cnt = 0; s_pos = 0; }
    __syncthreads();

    // ---- single HBM read: encode -> LDS, positive-only histogram from registers ----
    unsigned* myh = hist + (wv & 1) * HW0;
    unsigned pcnt = 0;
    #pragma unroll
    for (int j = 0; j < NCHUNK; ++j) {
        uint4 v = xrow[tid + j * TPB];
        uint4 k;
        k.x = enc(v.x); k.y = enc(v.y); k.z = enc(v.z); k.w = enc(v.w);
        ((uint4*)keys)[tid + j * TPB] = k;
        pcnt += (k.x >> 31) + (k.y >> 31) + (k.z >> 31) + (k.w >> 31);
        if (k.x >> 31) atomicAdd(&myh[k.x >> 22], 1u << (((k.x >> 21) & 1u) << 4));
        if (k.y >> 31) atomicAdd(&myh[k.y >> 22], 1u << (((k.y >> 21) & 1u) << 4));
        if (k.z >> 31) atomicAdd(&myh[k.z >> 22], 1u << (((k.z >> 21) & 1u) << 4));
        if (k.w >> 31) atomicAdd(&myh[k.w >> 22], 1u << (((k.w >> 21) & 1u) << 4));
    }
    #pragma unroll
    for (int s = 1; s < 64; s <<= 1) pcnt += __shfl_down(pcnt, s);
    if (lane == 0) atomicAdd(&s_pos, pcnt);
    __syncthreads();

    unsigned pref, kcur, eqc;
    if (s_pos < KTOP) {
        // ---- rare fallback: add negative keys, then scan full 2048 bins ----
        for (int i = tid; i < NCOL; i += TPB) {
            unsigned k = keys[i];
            if (!(k >> 31)) atomicAdd(&myh[k >> 22], 1u << (((k >> 21) & 1u) << 4));
        }
        __syncthreads();
        unsigned b, kk, e;
        boundary_scan(hist, lane, KTOP, 0, 16, b, kk, e);
        pref = b << 21; kcur = kk; eqc = e;
    } else {
        // ---- common path: scan positive half (1024 bins = words 512..1023) ----
        unsigned b, kk, e;
        boundary_scan(hist, lane, KTOP, 512, 8, b, kk, e);
        pref = b << 21; kcur = kk; eqc = e;
    }

    bool done = (kcur == eqc);   // keep whole boundary bin: T = bin floor

    if (!done) {
        // ---- extract boundary-bin candidates from LDS keys ----
        const unsigned bin0 = pref >> 21;
        #pragma unroll
        for (int j = 0; j < NCHUNK; ++j) {
            uint4 k = ((const uint4*)keys)[tid + j * TPB];
            if ((k.x >> 21) == bin0) { unsigned i = atomicAdd(&s_cnt, 1u); if (i < CAP) cand[i] = k.x; }
            if ((k.y >> 21) == bin0) { unsigned i = atomicAdd(&s_cnt, 1u); if (i < CAP) cand[i] = k.y; }
            if ((k.z >> 21) == bin0) { unsigned i = atomicAdd(&s_cnt, 1u); if (i < CAP) cand[i] = k.z; }
            if ((k.w >> 21) == bin0) { unsigned i = atomicAdd(&s_cnt, 1u); if (i < CAP) cand[i] = k.w; }
        }
        __syncthreads();
        const unsigned mtot = s_cnt;
        const bool use_list = (mtot <= CAP);

        // ---- passes 1-3: 7 bits each over candidate list (LDS-keys fallback) ----
        for (int p = 1; p <= 3 && !done; ++p) {
            const int shift = 21 - 7 * p;        // 14, 7, 0
            __syncthreads();
            for (int i = tid; i < 128; i += TPB) hist[i] = 0;
            __syncthreads();
            if (use_list) {
                for (unsigned i = tid; i < mtot; i += TPB) {
                    unsigned k = cand[i];
                    if (((k ^ pref) >> (shift + 7)) == 0)
                        atomicAdd(&hist[(k >> shift) & 0x7Fu], 1u);
                }
            } else {
                for (int i = tid; i < NCOL; i += TPB) {
                    unsigned k = keys[i];
                    if (((k ^ pref) >> (shift + 7)) == 0)
                        atomicAdd(&hist[(k >> shift) & 0x7Fu], 1u);
                }
            }
            __syncthreads();
            // 128-bin boundary scan; lane owns bins 2*lane, 2*lane+1
            unsigned t0 = hist[2 * lane], t1 = hist[2 * lane + 1];
            unsigned own = t0 + t1, incl = own;
            #pragma unroll
            for (int s = 1; s < 64; s <<= 1) {
                unsigned v = __shfl_down(incl, s);
                if (lane + s < 64) incl += v;
            }
            unsigned above = incl - own;
            unsigned C1 = above + t1;
            unsigned C0 = C1 + t0;
            bool h1 = (above < kcur) && (C1 >= kcur);
            bool h0 = (C1 < kcur) && (C0 >= kcur);
            unsigned mybin = h1 ? (2u * lane + 1u) : (2u * lane);
            unsigned myk   = h1 ? (kcur - above) : (kcur - C1);
            unsigned myeq  = h1 ? t1 : t0;
            unsigned long long bal = __ballot(h0 || h1);
            int L = __ffsll((long long)bal) - 1;
            pref |= __shfl(mybin, L) << shift;
            kcur  = __shfl(myk, L);
            eqc   = __shfl(myeq, L);
            if (kcur == eqc) done = true;
        }
    }

    const unsigned T = pref;
    const unsigned krem = kcur;

    if (done || krem == eqc) {
        // ---- fast path: keep everything >= T, from LDS ----
        #pragma unroll
        for (int j = 0; j < NCHUNK; ++j) {
            uint4 k = ((const uint4*)keys)[tid + j * TPB];
            uint4 o;
            o.x = (k.x >= T) ? dec(k.x) : 0u;
            o.y = (k.y >= T) ? dec(k.y) : 0u;
            o.z = (k.z >= T) ? dec(k.z) : 0u;
            o.w = (k.w >= T) ? dec(k.w) : 0u;
            orow[tid + j * TPB] = o;
        }
    } else {
        // ---- rare stable tie path: keep first krem equals in column order ----
        unsigned* scan_arr = hist;               // reuse (>= TPB words)
        unsigned run = 0;
        for (int j = 0; j < NCHUNK; ++j) {
            uint4 k = ((const uint4*)keys)[tid + j * TPB];
            unsigned e0 = (k.x == T), e1 = (k.y == T), e2 = (k.z == T), e3 = (k.w == T);
            unsigned le = e0 + e1 + e2 + e3;
            __syncthreads();
            scan_arr[tid] = le;
            __syncthreads();
            for (int s = 1; s < TPB; s <<= 1) {
                unsigned t = (tid >= s) ? scan_arr[tid - s] : 0u;
                __syncthreads();
                scan_arr[tid] += t;
                __syncthreads();
            }
            unsigned excl = scan_arr[tid] - le;
            unsigned total = scan_arr[TPB - 1];
            unsigned r0 = run + excl;
            unsigned r1 = r0 + e0, r2 = r1 + e1, r3 = r2 + e2;
            uint4 o;
            o.x = (k.x > T || (e0 && r0 < krem)) ? dec(k.x) : 0u;
            o.y = (k.y > T || (e1 && r1 < krem)) ? dec(k.y) : 0u;
            o.z = (k.z > T || (e2 && r2 < krem)) ? dec(k.z) : 0u;
            o.w = (k.w > T || (e3 && r3 < krem)) ? dec(k.w) : 0u;
            orow[tid + j * TPB] = o;
            run += total;
        }
    }
}

extern "C" void kernel_launch(void* const* d_in, const int* in_sizes, int n_in,
                              void* d_out, int out_size, void* d_ws, size_t ws_size,
                              hipStream_t stream) {
    const float* x = (const float*)d_in[0];
    float* out = (float*)d_out;
    const int B = in_sizes[0] / NCOL;   // 4096 rows
    topk_act_kernel<<<B, TPB, NCOL * sizeof(unsigned), stream>>>(x, out);
}

// Round 6
// 120.155 us; speedup vs baseline: 1.7319x; 1.1025x over previous
//
#include <hip/hip_runtime.h>

#define KTOP 100
#define NCOL 16384
#define TPB  1024
#define NCHUNK (NCOL / (TPB * 4))   // 4 uint4 per thread
#define HW0  1032                   // packed fallback: per-copy stride, 1024 words (2048 bins) + 8 pad
#define HST  520                    // common path: per-copy stride, 512 words + 8 pad
#define CAP  1024                   // candidate list capacity
#define T0   0xC0000000u            // enc(+2.0f): multiple of 2^21 -> aligns with bin 1536
#define BIN0 1536u

// order-preserving key transform: a<b (float) <=> enc(a)<enc(b) (uint)
__device__ __forceinline__ unsigned enc(unsigned u) {
    return u ^ (((unsigned)((int)u >> 31)) | 0x80000000u);
}
__device__ __forceinline__ unsigned dec(unsigned k) {
    return k ^ ((k & 0x80000000u) ? 0x80000000u : 0xFFFFFFFFu);
}

// packed-16 boundary scan over 2048 bins (fallback path), 2 copies at stride HW0
__device__ __forceinline__ void boundary_scan_packed(const unsigned* hist, int lane, unsigned kcur,
                                                     unsigned& obin, unsigned& ok, unsigned& oeq) {
    unsigned own = 0;
    #pragma unroll
    for (int w = 0; w < 16; ++w) {
        unsigned s = hist[16 * lane + w] + hist[HW0 + 16 * lane + w];
        own += (s & 0xFFFFu) + (s >> 16);
    }
    unsigned incl = own;
    #pragma unroll
    for (int s = 1; s < 64; s <<= 1) {
        unsigned v = __shfl_down(incl, s);
        if (lane + s < 64) incl += v;
    }
    unsigned above = incl - own;
    bool hit = (above < kcur) && (above + own >= kcur);
    unsigned long long bal = __ballot(hit);
    int L = __ffsll((long long)bal) - 1;
    unsigned run = __shfl(above, L);
    unsigned sbin = 0, sk = 1, seq = 1;
    for (int w = 15; w >= 0; --w) {
        unsigned s = hist[16 * L + w] + hist[HW0 + 16 * L + w];
        unsigned chi = s >> 16, clo = s & 0xFFFFu;
        unsigned r1 = run + chi;
        if (run < kcur && r1 >= kcur) { sbin = 32u * L + 2u * w + 1u; sk = kcur - run; seq = chi; }
        unsigned r2 = r1 + clo;
        if (r1 < kcur && r2 >= kcur) { sbin = 32u * L + 2u * w;       sk = kcur - r1;  seq = clo; }
        run = r2;
    }
    obin = sbin; ok = sk; oeq = seq;
}

__global__ __launch_bounds__(TPB, 8)
void topk_act_kernel(const float* __restrict__ x, float* __restrict__ out) {
    extern __shared__ unsigned keys[];       // 64 KB encoded row
    __shared__ unsigned hist[2 * HW0];       // 8.25 KB (covers packed fallback; common path uses 2*HST)
    __shared__ unsigned cand[CAP];           // 4 KB
    __shared__ unsigned s_cnt, s_pos;

    const int row  = blockIdx.x;
    const int tid  = threadIdx.x;
    const int lane = tid & 63;
    const int wv   = tid >> 6;

    const uint4* __restrict__ xrow = (const uint4*)(x + (size_t)row * NCOL);
    uint4* __restrict__ orow = (uint4*)(out + (size_t)row * NCOL);

    for (int i = tid; i < 2 * HST; i += TPB) hist[i] = 0;
    if (tid == 0) { s_cnt = 0; s_pos = 0; }
    __syncthreads();

    // ---- single HBM read: encode -> LDS; histogram ONLY keys >= 2.0 (≈373/row for N(0,1)) ----
    unsigned* myh = hist + (wv & 1) * HST;
    unsigned pcnt = 0;
    #pragma unroll
    for (int j = 0; j < NCHUNK; ++j) {
        uint4 v = xrow[tid + j * TPB];
        uint4 k;
        k.x = enc(v.x); k.y = enc(v.y); k.z = enc(v.z); k.w = enc(v.w);
        ((uint4*)keys)[tid + j * TPB] = k;
        pcnt += (k.x >= T0) + (k.y >= T0) + (k.z >= T0) + (k.w >= T0);
        if (k.x >= T0) atomicAdd(&myh[(k.x >> 21) - BIN0], 1u);
        if (k.y >= T0) atomicAdd(&myh[(k.y >> 21) - BIN0], 1u);
        if (k.z >= T0) atomicAdd(&myh[(k.z >> 21) - BIN0], 1u);
        if (k.w >= T0) atomicAdd(&myh[(k.w >> 21) - BIN0], 1u);
    }
    #pragma unroll
    for (int s = 1; s < 64; s <<= 1) pcnt += __shfl_down(pcnt, s);
    if (lane == 0) atomicAdd(&s_pos, pcnt);
    __syncthreads();

    unsigned pref, kcur, eqc;
    if (s_pos >= KTOP) {
        // ---- common path: boundary scan over 512 unpacked bins; lane owns 8 ----
        unsigned own = 0;
        #pragma unroll
        for (int w = 0; w < 8; ++w) own += hist[8 * lane + w] + hist[HST + 8 * lane + w];
        unsigned incl = own;
        #pragma unroll
        for (int s = 1; s < 64; s <<= 1) {
            unsigned v = __shfl_down(incl, s);
            if (lane + s < 64) incl += v;
        }
        unsigned above = incl - own;
        bool hit = (above < KTOP) && (above + own >= KTOP);
        unsigned long long bal = __ballot(hit);
        int L = __ffsll((long long)bal) - 1;
        unsigned run = __shfl(above, L);
        unsigned sbin = 0, sk = 1, seq = 1;
        for (int w = 7; w >= 0; --w) {
            unsigned c = hist[8 * L + w] + hist[HST + 8 * L + w];
            unsigned r = run + c;
            if (run < KTOP && r >= KTOP) { sbin = 8u * L + (unsigned)w; sk = KTOP - run; seq = c; }
            run = r;
        }
        pref = (sbin + BIN0) << 21; kcur = sk; eqc = seq;
    } else {
        // ---- rare fallback (data not N(0,1)-like): full packed 2048-bin histogram from LDS ----
        for (int i = tid; i < 2 * HW0; i += TPB) hist[i] = 0;
        __syncthreads();
        unsigned* mh = hist + (wv & 1) * HW0;
        for (int i = tid; i < NCOL; i += TPB) {
            unsigned k = keys[i];
            atomicAdd(&mh[k >> 22], 1u << (((k >> 21) & 1u) << 4));
        }
        __syncthreads();
        unsigned b, kk, e;
        boundary_scan_packed(hist, lane, KTOP, b, kk, e);
        pref = b << 21; kcur = kk; eqc = e;
    }

    bool done = (kcur == eqc);   // keep whole boundary bin: T = bin floor

    if (!done) {
        // ---- extract boundary-bin candidates from LDS keys (own slots only) ----
        const unsigned bin0 = pref >> 21;
        #pragma unroll
        for (int j = 0; j < NCHUNK; ++j) {
            uint4 k = ((const uint4*)keys)[tid + j * TPB];
            if ((k.x >> 21) == bin0) { unsigned i = atomicAdd(&s_cnt, 1u); if (i < CAP) cand[i] = k.x; }
            if ((k.y >> 21) == bin0) { unsigned i = atomicAdd(&s_cnt, 1u); if (i < CAP) cand[i] = k.y; }
            if ((k.z >> 21) == bin0) { unsigned i = atomicAdd(&s_cnt, 1u); if (i < CAP) cand[i] = k.z; }
            if ((k.w >> 21) == bin0) { unsigned i = atomicAdd(&s_cnt, 1u); if (i < CAP) cand[i] = k.w; }
        }
        __syncthreads();
        const unsigned mtot = s_cnt;
        const bool use_list = (mtot <= CAP);

        // ---- passes 1-3: 7 bits each over candidate list (LDS-keys fallback) ----
        for (int p = 1; p <= 3 && !done; ++p) {
            const int shift = 21 - 7 * p;        // 14, 7, 0
            __syncthreads();
            for (int i = tid; i < 128; i += TPB) hist[i] = 0;
            __syncthreads();
            if (use_list) {
                for (unsigned i = tid; i < mtot; i += TPB) {
                    unsigned k = cand[i];
                    if (((k ^ pref) >> (shift + 7)) == 0)
                        atomicAdd(&hist[(k >> shift) & 0x7Fu], 1u);
                }
            } else {
                for (int i = tid; i < NCOL; i += TPB) {
                    unsigned k = keys[i];
                    if (((k ^ pref) >> (shift + 7)) == 0)
                        atomicAdd(&hist[(k >> shift) & 0x7Fu], 1u);
                }
            }
            __syncthreads();
            unsigned t0 = hist[2 * lane], t1 = hist[2 * lane + 1];
            unsigned own = t0 + t1, incl = own;
            #pragma unroll
            for (int s = 1; s < 64; s <<= 1) {
                unsigned v = __shfl_down(incl, s);
                if (lane + s < 64) incl += v;
            }
            unsigned above = incl - own;
            unsigned C1 = above + t1;
            unsigned C0 = C1 + t0;
            bool h1 = (above < kcur) && (C1 >= kcur);
            bool h0 = (C1 < kcur) && (C0 >= kcur);
            unsigned mybin = h1 ? (2u * lane + 1u) : (2u * lane);
            unsigned myk   = h1 ? (kcur - above) : (kcur - C1);
            unsigned myeq  = h1 ? t1 : t0;
            unsigned long long bal = __ballot(h0 || h1);
            int L = __ffsll((long long)bal) - 1;
            pref |= __shfl(mybin, L) << shift;
            kcur  = __shfl(myk, L);
            eqc   = __shfl(myeq, L);
            if (kcur == eqc) done = true;
        }
    }

    const unsigned T = pref;
    const unsigned krem = kcur;

    if (done || krem == eqc) {
        // ---- fast path: keep everything >= T, from LDS (own slots) ----
        #pragma unroll
        for (int j = 0; j < NCHUNK; ++j) {
            uint4 k = ((const uint4*)keys)[tid + j * TPB];
            uint4 o;
            o.x = (k.x >= T) ? dec(k.x) : 0u;
            o.y = (k.y >= T) ? dec(k.y) : 0u;
            o.z = (k.z >= T) ? dec(k.z) : 0u;
            o.w = (k.w >= T) ? dec(k.w) : 0u;
            orow[tid + j * TPB] = o;
        }
    } else {
        // ---- rare stable tie path: keep first krem equals in column order ----
        unsigned* scan_arr = hist;               // reuse (>= TPB words)
        unsigned run = 0;
        for (int j = 0; j < NCHUNK; ++j) {
            uint4 k = ((const uint4*)keys)[tid + j * TPB];
            unsigned e0 = (k.x == T), e1 = (k.y == T), e2 = (k.z == T), e3 = (k.w == T);
            unsigned le = e0 + e1 + e2 + e3;
            __syncthreads();
            scan_arr[tid] = le;
            __syncthreads();
            for (int s = 1; s < TPB; s <<= 1) {
                unsigned t = (tid >= s) ? scan_arr[tid - s] : 0u;
                __syncthreads();
                scan_arr[tid] += t;
                __syncthreads();
            }
            unsigned excl = scan_arr[tid] - le;
            unsigned total = scan_arr[TPB - 1];
            unsigned r0 = run + excl;
            unsigned r1 = r0 + e0, r2 = r1 + e1, r3 = r2 + e2;
            uint4 o;
            o.x = (k.x > T || (e0 && r0 < krem)) ? dec(k.x) : 0u;
            o.y = (k.y > T || (e1 && r1 < krem)) ? dec(k.y) : 0u;
            o.z = (k.z > T || (e2 && r2 < krem)) ? dec(k.z) : 0u;
            o.w = (k.w > T || (e3 && r3 < krem)) ? dec(k.w) : 0u;
            orow[tid + j * TPB] = o;
            run += total;
        }
    }
}

extern "C" void kernel_launch(void* const* d_in, const int* in_sizes, int n_in,
                              void* d_out, int out_size, void* d_ws, size_t ws_size,
                              hipStream_t stream) {
    const float* x = (const float*)d_in[0];
    float* out = (float*)d_out;
    const int B = in_sizes[0] / NCOL;   // 4096 rows
    topk_act_kernel<<<B, TPB, NCOL * sizeof(unsigned), stream>>>(x, out);
}

// Round 7
// 110.823 us; speedup vs baseline: 1.8778x; 1.0842x over previous
//
#include <hip/hip_runtime.h>

#define KTOP 100
#define NCOL 16384
#define TPB  1024
#define NCHUNK (NCOL / (TPB * 4))   // 4 uint4 (16 values) per thread, held in registers
#define HW0  1032                   // packed fallback: per-copy stride, 1024 words (2048 bins) + 8 pad
#define HST  520                    // common path: per-copy stride, 512 words + 8 pad
#define CAP  1024                   // candidate list capacity
#define T0   0xC0000000u            // enc(+2.0f): multiple of 2^21 -> aligns with bin 1536
#define BIN0 1536u

// order-preserving key transform: a<b (float) <=> enc(a)<enc(b) (uint)
__device__ __forceinline__ unsigned enc(unsigned u) {
    return u ^ (((unsigned)((int)u >> 31)) | 0x80000000u);
}
__device__ __forceinline__ unsigned dec(unsigned k) {
    return k ^ ((k & 0x80000000u) ? 0x80000000u : 0xFFFFFFFFu);
}

// packed-16 boundary scan over 2048 bins (fallback path), 2 copies at stride HW0
__device__ __forceinline__ void boundary_scan_packed(const unsigned* hist, int lane, unsigned kcur,
                                                     unsigned& obin, unsigned& ok, unsigned& oeq) {
    unsigned own = 0;
    #pragma unroll
    for (int w = 0; w < 16; ++w) {
        unsigned s = hist[16 * lane + w] + hist[HW0 + 16 * lane + w];
        own += (s & 0xFFFFu) + (s >> 16);
    }
    unsigned incl = own;
    #pragma unroll
    for (int s = 1; s < 64; s <<= 1) {
        unsigned v = __shfl_down(incl, s);
        if (lane + s < 64) incl += v;
    }
    unsigned above = incl - own;
    bool hit = (above < kcur) && (above + own >= kcur);
    unsigned long long bal = __ballot(hit);
    int L = __ffsll((long long)bal) - 1;
    unsigned run = __shfl(above, L);
    unsigned sbin = 0, sk = 1, seq = 1;
    for (int w = 15; w >= 0; --w) {
        unsigned s = hist[16 * L + w] + hist[HW0 + 16 * L + w];
        unsigned chi = s >> 16, clo = s & 0xFFFFu;
        unsigned r1 = run + chi;
        if (run < kcur && r1 >= kcur) { sbin = 32u * L + 2u * w + 1u; sk = kcur - run; seq = chi; }
        unsigned r2 = r1 + clo;
        if (r1 < kcur && r2 >= kcur) { sbin = 32u * L + 2u * w;       sk = kcur - r1;  seq = clo; }
        run = r2;
    }
    obin = sbin; ok = sk; oeq = seq;
}

__global__ __launch_bounds__(TPB, 8)
void topk_act_kernel(const float* __restrict__ x, float* __restrict__ out) {
    __shared__ unsigned hist[2 * HW0];       // 8.25 KB (fallback needs 2*HW0; common uses 2*HST; tie path reuses)
    __shared__ unsigned cand[CAP];           // 4 KB
    __shared__ unsigned s_cnt, s_pos;

    const int row  = blockIdx.x;
    const int tid  = threadIdx.x;
    const int lane = tid & 63;
    const int wv   = tid >> 6;

    const uint4* __restrict__ xrow = (const uint4*)(x + (size_t)row * NCOL);
    uint4* __restrict__ orow = (uint4*)(out + (size_t)row * NCOL);

    for (int i = tid; i < 2 * HST; i += TPB) hist[i] = 0;
    if (tid == 0) { s_cnt = 0; s_pos = 0; }
    __syncthreads();

    // ---- single HBM read -> registers; histogram ONLY keys >= 2.0 (≈373/row for N(0,1)) ----
    unsigned* myh = hist + (wv & 1) * HST;
    uint4 kv[NCHUNK];
    unsigned pcnt = 0;
    #pragma unroll
    for (int j = 0; j < NCHUNK; ++j) {
        uint4 v = xrow[tid + j * TPB];
        kv[j].x = enc(v.x); kv[j].y = enc(v.y); kv[j].z = enc(v.z); kv[j].w = enc(v.w);
        pcnt += (kv[j].x >= T0) + (kv[j].y >= T0) + (kv[j].z >= T0) + (kv[j].w >= T0);
        if (kv[j].x >= T0) atomicAdd(&myh[(kv[j].x >> 21) - BIN0], 1u);
        if (kv[j].y >= T0) atomicAdd(&myh[(kv[j].y >> 21) - BIN0], 1u);
        if (kv[j].z >= T0) atomicAdd(&myh[(kv[j].z >> 21) - BIN0], 1u);
        if (kv[j].w >= T0) atomicAdd(&myh[(kv[j].w >> 21) - BIN0], 1u);
    }
    #pragma unroll
    for (int s = 1; s < 64; s <<= 1) pcnt += __shfl_down(pcnt, s);
    if (lane == 0) atomicAdd(&s_pos, pcnt);
    __syncthreads();

    unsigned pref, kcur, eqc;
    if (s_pos >= KTOP) {
        // ---- common path: boundary scan over 512 unpacked bins; lane owns 8 ----
        unsigned own = 0;
        #pragma unroll
        for (int w = 0; w < 8; ++w) own += hist[8 * lane + w] + hist[HST + 8 * lane + w];
        unsigned incl = own;
        #pragma unroll
        for (int s = 1; s < 64; s <<= 1) {
            unsigned v = __shfl_down(incl, s);
            if (lane + s < 64) incl += v;
        }
        unsigned above = incl - own;
        bool hit = (above < KTOP) && (above + own >= KTOP);
        unsigned long long bal = __ballot(hit);
        int L = __ffsll((long long)bal) - 1;
        unsigned run = __shfl(above, L);
        unsigned sbin = 0, sk = 1, seq = 1;
        for (int w = 7; w >= 0; --w) {
            unsigned c = hist[8 * L + w] + hist[HST + 8 * L + w];
            unsigned r = run + c;
            if (run < KTOP && r >= KTOP) { sbin = 8u * L + (unsigned)w; sk = KTOP - run; seq = c; }
            run = r;
        }
        pref = (sbin + BIN0) << 21; kcur = sk; eqc = seq;
    } else {
        // ---- rare fallback: full packed 2048-bin histogram from registers ----
        __syncthreads();
        for (int i = tid; i < 2 * HW0; i += TPB) hist[i] = 0;
        __syncthreads();
        unsigned* mh = hist + (wv & 1) * HW0;
        #pragma unroll
        for (int j = 0; j < NCHUNK; ++j) {
            atomicAdd(&mh[kv[j].x >> 22], 1u << (((kv[j].x >> 21) & 1u) << 4));
            atomicAdd(&mh[kv[j].y >> 22], 1u << (((kv[j].y >> 21) & 1u) << 4));
            atomicAdd(&mh[kv[j].z >> 22], 1u << (((kv[j].z >> 21) & 1u) << 4));
            atomicAdd(&mh[kv[j].w >> 22], 1u << (((kv[j].w >> 21) & 1u) << 4));
        }
        __syncthreads();
        unsigned b, kk, e;
        boundary_scan_packed(hist, lane, KTOP, b, kk, e);
        pref = b << 21; kcur = kk; eqc = e;
    }

    bool done = (kcur == eqc);   // keep whole boundary bin: T = bin floor

    if (!done) {
        // ---- extract boundary-bin candidates from registers into LDS list ----
        const unsigned bin0 = pref >> 21;
        #pragma unroll
        for (int j = 0; j < NCHUNK; ++j) {
            if ((kv[j].x >> 21) == bin0) { unsigned i = atomicAdd(&s_cnt, 1u); if (i < CAP) cand[i] = kv[j].x; }
            if ((kv[j].y >> 21) == bin0) { unsigned i = atomicAdd(&s_cnt, 1u); if (i < CAP) cand[i] = kv[j].y; }
            if ((kv[j].z >> 21) == bin0) { unsigned i = atomicAdd(&s_cnt, 1u); if (i < CAP) cand[i] = kv[j].z; }
            if ((kv[j].w >> 21) == bin0) { unsigned i = atomicAdd(&s_cnt, 1u); if (i < CAP) cand[i] = kv[j].w; }
        }
        __syncthreads();
        const unsigned mtot = s_cnt;
        const bool use_list = (mtot <= CAP);

        // ---- passes 1-3: 7 bits each over candidate list (register fallback if overflow) ----
        for (int p = 1; p <= 3 && !done; ++p) {
            const int shift = 21 - 7 * p;        // 14, 7, 0
            __syncthreads();
            for (int i = tid; i < 128; i += TPB) hist[i] = 0;
            __syncthreads();
            if (use_list) {
                for (unsigned i = tid; i < mtot; i += TPB) {
                    unsigned k = cand[i];
                    if (((k ^ pref) >> (shift + 7)) == 0)
                        atomicAdd(&hist[(k >> shift) & 0x7Fu], 1u);
                }
            } else {
                #pragma unroll
                for (int j = 0; j < NCHUNK; ++j) {
                    if (((kv[j].x ^ pref) >> (shift + 7)) == 0) atomicAdd(&hist[(kv[j].x >> shift) & 0x7Fu], 1u);
                    if (((kv[j].y ^ pref) >> (shift + 7)) == 0) atomicAdd(&hist[(kv[j].y >> shift) & 0x7Fu], 1u);
                    if (((kv[j].z ^ pref) >> (shift + 7)) == 0) atomicAdd(&hist[(kv[j].z >> shift) & 0x7Fu], 1u);
                    if (((kv[j].w ^ pref) >> (shift + 7)) == 0) atomicAdd(&hist[(kv[j].w >> shift) & 0x7Fu], 1u);
                }
            }
            __syncthreads();
            unsigned t0 = hist[2 * lane], t1 = hist[2 * lane + 1];
            unsigned own = t0 + t1, incl = own;
            #pragma unroll
            for (int s = 1; s < 64; s <<= 1) {
                unsigned v = __shfl_down(incl, s);
                if (lane + s < 64) incl += v;
            }
            unsigned above = incl - own;
            unsigned C1 = above + t1;
            unsigned C0 = C1 + t0;
            bool h1 = (above < kcur) && (C1 >= kcur);
            bool h0 = (C1 < kcur) && (C0 >= kcur);
            unsigned mybin = h1 ? (2u * lane + 1u) : (2u * lane);
            unsigned myk   = h1 ? (kcur - above) : (kcur - C1);
            unsigned myeq  = h1 ? t1 : t0;
            unsigned long long bal = __ballot(h0 || h1);
            int L = __ffsll((long long)bal) - 1;
            pref |= __shfl(mybin, L) << shift;
            kcur  = __shfl(myk, L);
            eqc   = __shfl(myeq, L);
            if (kcur == eqc) done = true;
        }
    }

    const unsigned T = pref;
    const unsigned krem = kcur;

    if (done || krem == eqc) {
        // ---- fast path: keep everything >= T, straight from registers ----
        #pragma unroll
        for (int j = 0; j < NCHUNK; ++j) {
            uint4 o;
            o.x = (kv[j].x >= T) ? dec(kv[j].x) : 0u;
            o.y = (kv[j].y >= T) ? dec(kv[j].y) : 0u;
            o.z = (kv[j].z >= T) ? dec(kv[j].z) : 0u;
            o.w = (kv[j].w >= T) ? dec(kv[j].w) : 0u;
            orow[tid + j * TPB] = o;
        }
    } else {
        // ---- rare stable tie path: keep first krem equals in column order ----
        unsigned* scan_arr = hist;               // reuse (2064 >= TPB words)
        unsigned run = 0;
        for (int j = 0; j < NCHUNK; ++j) {
            unsigned e0 = (kv[j].x == T), e1 = (kv[j].y == T), e2 = (kv[j].z == T), e3 = (kv[j].w == T);
            unsigned le = e0 + e1 + e2 + e3;
            __syncthreads();
            scan_arr[tid] = le;
            __syncthreads();
            for (int s = 1; s < TPB; s <<= 1) {
                unsigned t = (tid >= s) ? scan_arr[tid - s] : 0u;
                __syncthreads();
                scan_arr[tid] += t;
                __syncthreads();
            }
            unsigned excl = scan_arr[tid] - le;
            unsigned total = scan_arr[TPB - 1];
            unsigned r0 = run + excl;
            unsigned r1 = r0 + e0, r2 = r1 + e1, r3 = r2 + e2;
            uint4 o;
            o.x = (kv[j].x > T || (e0 && r0 < krem)) ? dec(kv[j].x) : 0u;
            o.y = (kv[j].y > T || (e1 && r1 < krem)) ? dec(kv[j].y) : 0u;
            o.z = (kv[j].z > T || (e2 && r2 < krem)) ? dec(kv[j].z) : 0u;
            o.w = (kv[j].w > T || (e3 && r3 < krem)) ? dec(kv[j].w) : 0u;
            orow[tid + j * TPB] = o;
            run += total;
        }
    }
}

extern "C" void kernel_launch(void* const* d_in, const int* in_sizes, int n_in,
                              void* d_out, int out_size, void* d_ws, size_t ws_size,
                              hipStream_t stream) {
    const float* x = (const float*)d_in[0];
    float* out = (float*)d_out;
    const int B = in_sizes[0] / NCOL;   // 4096 rows
    topk_act_kernel<<<B, TPB, 0, stream>>>(x, out);
}